// Round 1
// baseline (2709.444 us; speedup 1.0000x reference)
//
#include <hip/hip_runtime.h>
#include <cmath>

#define NUM_LEVELS 16
#define TABLE_SIZE_U (1u << 20)
#define TABLE_MASK (TABLE_SIZE_U - 1u)
#define P2 2654435761u
#define P3 805459861u

struct ResParams { int res[NUM_LEVELS]; };

__global__ __launch_bounds__(256) void hashenc_kernel(
    const float* __restrict__ pos,
    const float* __restrict__ tables,
    float* __restrict__ out,
    int n_points,
    ResParams rp)
{
    int tid = blockIdx.x * blockDim.x + threadIdx.x;
    int total = n_points * NUM_LEVELS;
    if (tid >= total) return;

    int p = tid >> 4;   // point index
    int l = tid & 15;   // level index

    // positions clipped to [0,1] (reference does jnp.clip first)
    float px = fminf(fmaxf(pos[p * 3 + 0], 0.0f), 1.0f);
    float py = fminf(fmaxf(pos[p * 3 + 1], 0.0f), 1.0f);
    float pz = fminf(fmaxf(pos[p * 3 + 2], 0.0f), 1.0f);

    int res = rp.res[l];
    float fres = (float)res;
    float sx = px * fres, sy = py * fres, sz = pz * fres;
    float fx = floorf(sx), fy = floorf(sy), fz = floorf(sz);
    // t from UNCLIPPED floor (matches reference ordering)
    float tx = sx - fx, ty = sy - fy, tz = sz - fz;
    // corner from clamped floor
    int cx = min(max((int)fx, 0), res - 1);
    int cy = min(max((int)fy, 0), res - 1);
    int cz = min(max((int)fz, 0), res - 1);

    // per-axis hash components (uint32 wraparound semantics match jnp.uint32)
    unsigned hx0 = (unsigned)cx;            // prime for x is 1
    unsigned hx1 = (unsigned)(cx + 1);
    unsigned hy0 = (unsigned)cy * P2;
    unsigned hy1 = (unsigned)(cy + 1) * P2;
    unsigned hz0 = (unsigned)cz * P3;
    unsigned hz1 = (unsigned)(cz + 1) * P3;

    const float2* __restrict__ tab =
        (const float2*)tables + (size_t)l * (size_t)TABLE_SIZE_U;

    // feats[i*4 + j*2 + k] for offsets (i,j,k) on (x,y,z)
    float2 f000 = tab[(hx0 + hy0 + hz0) & TABLE_MASK];
    float2 f001 = tab[(hx0 + hy0 + hz1) & TABLE_MASK];
    float2 f010 = tab[(hx0 + hy1 + hz0) & TABLE_MASK];
    float2 f011 = tab[(hx0 + hy1 + hz1) & TABLE_MASK];
    float2 f100 = tab[(hx1 + hy0 + hz0) & TABLE_MASK];
    float2 f101 = tab[(hx1 + hy0 + hz1) & TABLE_MASK];
    float2 f110 = tab[(hx1 + hy1 + hz0) & TABLE_MASK];
    float2 f111 = tab[(hx1 + hy1 + hz1) & TABLE_MASK];

    // literal replication of the reference blend (its weight<->axis mapping
    // is intentionally copied as-is: tx blends k-pairs, ty blends i, tz blends j)
    float wx0 = 1.0f - tx, wy0 = 1.0f - ty, wz0 = 1.0f - tz;
    float c00x = f000.x * wx0 + f001.x * tx;
    float c00y = f000.y * wx0 + f001.y * tx;
    float c01x = f010.x * wx0 + f011.x * tx;
    float c01y = f010.y * wx0 + f011.y * tx;
    float c10x = f100.x * wx0 + f101.x * tx;
    float c10y = f100.y * wx0 + f101.y * tx;
    float c11x = f110.x * wx0 + f111.x * tx;
    float c11y = f110.y * wx0 + f111.y * tx;
    float c0x = c00x * wy0 + c10x * ty;
    float c0y = c00y * wy0 + c10y * ty;
    float c1x = c01x * wy0 + c11x * ty;
    float c1y = c01y * wy0 + c11y * ty;
    float ox = c0x * wz0 + c1x * tz;
    float oy = c0y * wz0 + c1y * tz;

    // out[p][l*2 + f] -> float2 store, fully coalesced (tid-contiguous)
    ((float2*)out)[tid] = make_float2(ox, oy);
}

extern "C" void kernel_launch(void* const* d_in, const int* in_sizes, int n_in,
                              void* d_out, int out_size, void* d_ws, size_t ws_size,
                              hipStream_t stream) {
    const float* pos    = (const float*)d_in[0];
    const float* tables = (const float*)d_in[1];
    float* out = (float*)d_out;

    int n_points = in_sizes[0] / 3;

    // Replicate numpy: _b = exp(log(2048/16)/15); res_l = int(16 * _b**l)
    // Host libm (same glibc numpy uses) to match truncation at the l=15
    // boundary (16*b^15 == 2048.0 +/- ~1e-12).
    ResParams rp;
    double b = exp(log(2048.0 / 16.0) / (double)(NUM_LEVELS - 1));
    for (int l = 0; l < NUM_LEVELS; ++l) {
        double r = 16.0 * pow(b, (double)l);
        rp.res[l] = (int)r;
    }

    long long total = (long long)n_points * NUM_LEVELS;
    int block = 256;
    int grid = (int)((total + block - 1) / block);
    hashenc_kernel<<<grid, block, 0, stream>>>(pos, tables, out, n_points, rp);
}

// Round 3
// 1937.249 us; speedup vs baseline: 1.3986x; 1.3986x over previous
//
#include <hip/hip_runtime.h>
#include <cmath>

#define NUM_LEVELS 16
#define TABLE_SIZE_U (1u << 20)
#define TABLE_MASK (TABLE_SIZE_U - 1u)
#define P2 2654435761u
#define P3 805459861u

typedef float vf2 __attribute__((ext_vector_type(2)));
typedef float vf4 __attribute__((ext_vector_type(4)));

struct ResParams { int res[NUM_LEVELS]; };

// Trilinear hash-grid interp for one (point, level). Replicates the
// reference blend literally (its weight<->axis mapping: tx blends the
// z-offset pairs, ty the x-offset, tz the y-offset -- copied as-is).
__device__ __forceinline__ vf2 hash_interp(
    const float* __restrict__ pos, const vf2* __restrict__ tab,
    int p, int res)
{
    float px = fminf(fmaxf(pos[p * 3 + 0], 0.0f), 1.0f);
    float py = fminf(fmaxf(pos[p * 3 + 1], 0.0f), 1.0f);
    float pz = fminf(fmaxf(pos[p * 3 + 2], 0.0f), 1.0f);

    float fres = (float)res;
    float sx = px * fres, sy = py * fres, sz = pz * fres;
    float fx = floorf(sx), fy = floorf(sy), fz = floorf(sz);
    float tx = sx - fx, ty = sy - fy, tz = sz - fz;   // from UNCLIPPED floor
    int cx = min(max((int)fx, 0), res - 1);
    int cy = min(max((int)fy, 0), res - 1);
    int cz = min(max((int)fz, 0), res - 1);

    unsigned hx0 = (unsigned)cx;              // prime_x = 1
    unsigned hx1 = (unsigned)(cx + 1);
    unsigned hy0 = (unsigned)cy * P2;
    unsigned hy1 = (unsigned)(cy + 1) * P2;
    unsigned hz0 = (unsigned)cz * P3;
    unsigned hz1 = (unsigned)(cz + 1) * P3;

    vf2 f000 = tab[(hx0 + hy0 + hz0) & TABLE_MASK];
    vf2 f001 = tab[(hx0 + hy0 + hz1) & TABLE_MASK];
    vf2 f010 = tab[(hx0 + hy1 + hz0) & TABLE_MASK];
    vf2 f011 = tab[(hx0 + hy1 + hz1) & TABLE_MASK];
    vf2 f100 = tab[(hx1 + hy0 + hz0) & TABLE_MASK];
    vf2 f101 = tab[(hx1 + hy0 + hz1) & TABLE_MASK];
    vf2 f110 = tab[(hx1 + hy1 + hz0) & TABLE_MASK];
    vf2 f111 = tab[(hx1 + hy1 + hz1) & TABLE_MASK];

    float wx0 = 1.0f - tx, wy0 = 1.0f - ty, wz0 = 1.0f - tz;
    vf2 c00 = f000 * wx0 + f001 * tx;
    vf2 c01 = f010 * wx0 + f011 * tx;
    vf2 c10 = f100 * wx0 + f101 * tx;
    vf2 c11 = f110 * wx0 + f111 * tx;
    vf2 c0 = c00 * wy0 + c10 * ty;
    vf2 c1 = c01 * wy0 + c11 * ty;
    return c0 * wz0 + c1 * tz;
}

// --- Path A kernel 1: level-blocked gather, level->XCD affinity ------------
// Block b: xcd = b&7 (MI355X round-robin dispatch), handles levels {xcd,
// 15-xcd} (cheap+expensive pair, byte-balanced). 256 consecutive points per
// block -> coalesced level-major write to ws. Nontemporal store keeps the
// 4 MiB per-XCD L2 free for table gathers.
__global__ __launch_bounds__(256) void gather_lvlmajor(
    const float* __restrict__ pos,
    const float* __restrict__ tables,
    vf2* __restrict__ ws2,
    int n_points, ResParams rp)
{
    int b = blockIdx.x;
    int xcd = b & 7;
    int j = b >> 3;
    int level = (j & 1) ? (15 - xcd) : xcd;
    int chunk = j >> 1;
    int p = chunk * 256 + threadIdx.x;
    if (p >= n_points) return;

    const vf2* tab = (const vf2*)tables + (size_t)level * TABLE_SIZE_U;
    vf2 r = hash_interp(pos, tab, p, rp.res[level]);
    __builtin_nontemporal_store(r, &ws2[(size_t)level * n_points + p]);
}

// --- Path A kernel 2: [L][N] vf2  ->  [N][L] layout, LDS tile transpose ----
__global__ __launch_bounds__(256) void transpose_out(
    const vf2* __restrict__ ws2,
    vf4* __restrict__ out4,
    int n_points)
{
    __shared__ float lds[NUM_LEVELS][514];   // 512 floats + 2 pad (bank spread)
    int p0 = blockIdx.x * 256;
    int t = threadIdx.x;
    int p = p0 + t;

    for (int l = 0; l < NUM_LEVELS; ++l) {
        vf2 v = (vf2)(0.0f, 0.0f);
        if (p < n_points)
            v = __builtin_nontemporal_load(&ws2[(size_t)l * n_points + p]);
        lds[l][t * 2]     = v.x;
        lds[l][t * 2 + 1] = v.y;
    }
    __syncthreads();

    // Coalesced vf4 stores: global float4 index = p0*8 + (t + jj*256).
    for (int jj = 0; jj < 8; ++jj) {
        int idx = t + jj * 256;      // within-tile float4 index
        int pi  = idx >> 3;          // point within tile
        int q   = idx & 7;           // which float4 of the 32-float row
        int gp  = p0 + pi;
        if (gp < n_points) {
            vf4 v;
            v.x = lds[2 * q][pi * 2];
            v.y = lds[2 * q][pi * 2 + 1];
            v.z = lds[2 * q + 1][pi * 2];
            v.w = lds[2 * q + 1][pi * 2 + 1];
            __builtin_nontemporal_store(v, &out4[(size_t)p0 * 8 + idx]);
        }
    }
}

// --- Path B (fallback if ws too small): round-1 direct kernel --------------
__global__ __launch_bounds__(256) void hashenc_direct(
    const float* __restrict__ pos,
    const float* __restrict__ tables,
    vf2* __restrict__ out2,
    int n_points, ResParams rp)
{
    int tid = blockIdx.x * blockDim.x + threadIdx.x;
    if (tid >= n_points * NUM_LEVELS) return;
    int p = tid >> 4;
    int l = tid & 15;
    const vf2* tab = (const vf2*)tables + (size_t)l * TABLE_SIZE_U;
    out2[tid] = hash_interp(pos, tab, p, rp.res[l]);
}

extern "C" void kernel_launch(void* const* d_in, const int* in_sizes, int n_in,
                              void* d_out, int out_size, void* d_ws, size_t ws_size,
                              hipStream_t stream) {
    const float* pos    = (const float*)d_in[0];
    const float* tables = (const float*)d_in[1];
    int n_points = in_sizes[0] / 3;

    // numpy-matching resolutions: int(16 * b**l), b = exp(log(128)/15)
    ResParams rp;
    double bb = exp(log(2048.0 / 16.0) / (double)(NUM_LEVELS - 1));
    for (int l = 0; l < NUM_LEVELS; ++l)
        rp.res[l] = (int)(16.0 * pow(bb, (double)l));

    size_t need = (size_t)n_points * NUM_LEVELS * sizeof(vf2);
    int nchunks = (n_points + 255) / 256;

    if (ws_size >= need) {
        gather_lvlmajor<<<nchunks * NUM_LEVELS, 256, 0, stream>>>(
            pos, tables, (vf2*)d_ws, n_points, rp);
        transpose_out<<<nchunks, 256, 0, stream>>>(
            (const vf2*)d_ws, (vf4*)d_out, n_points);
    } else {
        long long total = (long long)n_points * NUM_LEVELS;
        int grid = (int)((total + 255) / 256);
        hashenc_direct<<<grid, 256, 0, stream>>>(
            pos, tables, (vf2*)d_out, n_points, rp);
    }
}